// Round 1
// baseline (36.284 us; speedup 1.0000x reference)
//
#include <hip/hip_runtime.h>

// Problem constants (from reference)
#define N_ 16
#define A_ 4096
#define G_ 256
#define C_ 80
#define ALPHA_ 0.25f
#define BIG_ 1e8f

__global__ __launch_bounds__(256) void cbppl_fused_kernel(
    const float* __restrict__ gt_padded,    // (N, G, 4)
    const float* __restrict__ prop_boxes,   // (N, A, 4)
    const float* __restrict__ pred_boxes,   // (N, A, 4)
    const float* __restrict__ class_logits, // (N, A, C)
    const int*   __restrict__ gt_masks,     // (N, G) bool->int32
    const int*   __restrict__ gt_classes,   // (N, G)
    float* __restrict__ out_cls,            // (N, A)
    float* __restrict__ out_proj)           // (N, A)
{
    __shared__ float4 s_gt[G_];
    __shared__ int    s_mask[G_];
    __shared__ int    s_cls[G_];

    const int blocksPerBatch = A_ / 256;          // 16
    const int n = blockIdx.x / blocksPerBatch;
    const int a = (blockIdx.x % blocksPerBatch) * 256 + threadIdx.x;
    const int t = threadIdx.x;

    // Stage gt data for this batch into LDS (G_ == blockDim.x == 256)
    s_gt[t]   = ((const float4*)gt_padded)[n * G_ + t];
    s_mask[t] = gt_masks[n * G_ + t];
    s_cls[t]  = gt_classes[n * G_ + t];
    __syncthreads();

    // ---- Phase 1: argmin over masked prop distances ----
    const float4 pb = ((const float4*)prop_boxes)[n * A_ + a];

    float mind = INFINITY;
    int   closest = 0;
    int   any = 0;
    #pragma unroll 8
    for (int g = 0; g < G_; ++g) {
        const float4 gb = s_gt[g];
        const int m = s_mask[g];
        any |= m;
        float d = fabsf(pb.x - gb.x) + fabsf(pb.y - gb.y)
                + fabsf(pb.z - gb.z) + fabsf(pb.w - gb.w);
        d = m ? d : BIG_;
        if (d < mind) { mind = d; closest = g; }   // strict < => first-occurrence argmin
    }

    // ---- Phase 2: projection loss at closest only ----
    const float4 qb = ((const float4*)pred_boxes)[n * A_ + a];
    const float4 cb = s_gt[closest];
    const int    cm = s_mask[closest];
    float pd = fabsf(qb.x - cb.x) + fabsf(qb.y - cb.y)
             + fabsf(qb.z - cb.z) + fabsf(qb.w - cb.w);
    const float proj = cm ? pd : 0.0f;

    // ---- Phase 3: sigmoid focal loss, mean over C ----
    const int nonempty = any;
    const int target   = nonempty ? s_cls[closest] : 0;

    const float4* lg = (const float4*)(class_logits + ((size_t)n * A_ + a) * C_);
    float acc = 0.0f;
    #pragma unroll
    for (int j = 0; j < C_ / 4; ++j) {
        const float4 x4 = lg[j];
        const float xs[4] = {x4.x, x4.y, x4.z, x4.w};
        #pragma unroll
        for (int k = 0; k < 4; ++k) {
            const int   c  = j * 4 + k;
            const float x  = xs[k];
            const float oh = (c == target) ? 1.0f : 0.0f;
            const float ax = fabsf(x);
            const float e  = expf(-ax);                 // exp(-|x|)
            const float ce = fmaxf(x, 0.0f) - x * oh + log1pf(e);
            const float p  = (x >= 0.0f) ? (1.0f / (1.0f + e))
                                         : (e / (1.0f + e));   // sigmoid(x)
            const float pt = oh ? p : (1.0f - p);
            const float om = 1.0f - pt;
            const float at = oh ? ALPHA_ : (1.0f - ALPHA_);
            acc += at * (ce * om * om);
        }
    }
    const float cls = acc * (1.0f / (float)C_);

    const int oidx = n * A_ + a;
    out_cls[oidx]  = nonempty ? cls : 0.0f;
    out_proj[oidx] = proj;
}

extern "C" void kernel_launch(void* const* d_in, const int* in_sizes, int n_in,
                              void* d_out, int out_size, void* d_ws, size_t ws_size,
                              hipStream_t stream) {
    const float* gt_padded    = (const float*)d_in[0];
    const float* prop_boxes   = (const float*)d_in[1];
    const float* pred_boxes   = (const float*)d_in[2];
    const float* class_logits = (const float*)d_in[3];
    const int*   gt_masks     = (const int*)d_in[4];
    const int*   gt_classes   = (const int*)d_in[5];

    float* out = (float*)d_out;
    float* out_cls  = out;             // classification_loss, (N, A)
    float* out_proj = out + N_ * A_;   // projection_loss,     (N, A)

    dim3 grid(N_ * (A_ / 256));
    dim3 block(256);
    cbppl_fused_kernel<<<grid, block, 0, stream>>>(
        gt_padded, prop_boxes, pred_boxes, class_logits,
        gt_masks, gt_classes, out_cls, out_proj);
}

// Round 2
// 15.811 us; speedup vs baseline: 2.2949x; 2.2949x over previous
//
#include <hip/hip_runtime.h>

// Problem constants (from reference)
#define N_ 16
#define A_ 4096
#define G_ 256
#define C_ 80
#define ALPHA_ 0.25f
#define BIG_ 1e8f

// 4 lanes cooperate per anchor: sub = lane & 3.
//  - g-loop split stride-4 across subs (keeps LDS reads in distinct banks)
//  - class-loop split in 20-class contiguous chunks (5x float4, coalesced)
// 64 anchors per 256-thread block -> 1024 blocks -> 4096 waves (50% occupancy)

__global__ __launch_bounds__(256) void cbppl_fused_kernel(
    const float* __restrict__ gt_padded,    // (N, G, 4)
    const float* __restrict__ prop_boxes,   // (N, A, 4)
    const float* __restrict__ pred_boxes,   // (N, A, 4)
    const float* __restrict__ class_logits, // (N, A, C)
    const int*   __restrict__ gt_masks,     // (N, G) bool->int32
    const int*   __restrict__ gt_classes,   // (N, G)
    float* __restrict__ out_cls,            // (N, A)
    float* __restrict__ out_proj)           // (N, A)
{
    __shared__ float4 s_gt[G_];
    __shared__ float  s_bias[G_];   // 0 if masked-in, BIG if masked-out
    __shared__ int    s_mask[G_];
    __shared__ int    s_cls[G_];

    const int t   = threadIdx.x;
    const int n   = blockIdx.x >> 6;                     // 64 blocks per batch
    const int a   = ((blockIdx.x & 63) << 6) + (t >> 2); // 64 anchors per block
    const int sub = t & 3;

    // Stage gt data for this batch into LDS (G_ == blockDim.x == 256)
    {
        const float4 g4 = ((const float4*)gt_padded)[n * G_ + t];
        const int    m  = gt_masks[n * G_ + t];
        s_gt[t]   = g4;
        s_bias[t] = m ? 0.0f : BIG_;
        s_mask[t] = m;
        s_cls[t]  = gt_classes[n * G_ + t];
    }
    __syncthreads();

    // ---- Phase 1: argmin over masked prop distances (stride-4 split) ----
    const float4 pb = ((const float4*)prop_boxes)[n * A_ + a];

    float mind    = INFINITY;
    int   closest = 0;
    #pragma unroll 8
    for (int g = sub; g < G_; g += 4) {
        const float4 gb = s_gt[g];
        float d = fabsf(pb.x - gb.x) + fabsf(pb.y - gb.y)
                + fabsf(pb.z - gb.z) + fabsf(pb.w - gb.w)
                + s_bias[g];
        if (d < mind) { mind = d; closest = g; }  // indices increase -> first occurrence kept
    }
    // Cross-lane argmin over the 4 subs; tie -> smaller index (first occurrence)
    #pragma unroll
    for (int off = 1; off < 4; off <<= 1) {
        const float od = __shfl_xor(mind, off, 64);
        const int   oc = __shfl_xor(closest, off, 64);
        if (od < mind || (od == mind && oc < closest)) { mind = od; closest = oc; }
    }
    // unmasked d <= 4 << BIG, so min < BIG  <=>  some mask set
    const int nonempty = (mind < BIG_);

    // ---- Phase 2: projection loss at closest only ----
    const float4 qb = ((const float4*)pred_boxes)[n * A_ + a];
    const float4 cb = s_gt[closest];
    const int    cm = s_mask[closest];
    const float  pd = fabsf(qb.x - cb.x) + fabsf(qb.y - cb.y)
                    + fabsf(qb.z - cb.z) + fabsf(qb.w - cb.w);
    const float proj = cm ? pd : 0.0f;

    // ---- Phase 3: sigmoid focal loss, 20 classes per sub-lane ----
    const int target = nonempty ? s_cls[closest] : 0;

    const float4* lg = (const float4*)(class_logits + ((size_t)(n * A_ + a)) * C_)
                     + sub * 5;
    float acc = 0.0f;
    #pragma unroll
    for (int j = 0; j < 5; ++j) {
        const float4 x4 = lg[j];
        const float xs[4] = {x4.x, x4.y, x4.z, x4.w};
        #pragma unroll
        for (int k = 0; k < 4; ++k) {
            const int   c  = sub * 20 + j * 4 + k;
            const float x  = xs[k];
            const float oh = (c == target) ? 1.0f : 0.0f;
            const float ax = fabsf(x);
            const float e  = __expf(-ax);                       // exp(-|x|)
            const float ce = fmaxf(x, 0.0f) - x * oh + __logf(1.0f + e);
            const float r  = __builtin_amdgcn_rcpf(1.0f + e);
            const float p  = (x >= 0.0f) ? r : e * r;           // sigmoid(x)
            const float pt = oh ? p : (1.0f - p);
            const float om = 1.0f - pt;
            const float at = oh ? ALPHA_ : (1.0f - ALPHA_);
            acc += at * (ce * om * om);
        }
    }
    // Sum partial focal losses across the 4 subs
    acc += __shfl_xor(acc, 1, 64);
    acc += __shfl_xor(acc, 2, 64);

    if (sub == 0) {
        const int oidx = n * A_ + a;
        out_cls[oidx]  = nonempty ? acc * (1.0f / (float)C_) : 0.0f;
        out_proj[oidx] = proj;
    }
}

extern "C" void kernel_launch(void* const* d_in, const int* in_sizes, int n_in,
                              void* d_out, int out_size, void* d_ws, size_t ws_size,
                              hipStream_t stream) {
    const float* gt_padded    = (const float*)d_in[0];
    const float* prop_boxes   = (const float*)d_in[1];
    const float* pred_boxes   = (const float*)d_in[2];
    const float* class_logits = (const float*)d_in[3];
    const int*   gt_masks     = (const int*)d_in[4];
    const int*   gt_classes   = (const int*)d_in[5];

    float* out = (float*)d_out;
    float* out_cls  = out;             // classification_loss, (N, A)
    float* out_proj = out + N_ * A_;   // projection_loss,     (N, A)

    dim3 grid(N_ * A_ / 64);           // 1024 blocks, 64 anchors each
    dim3 block(256);
    cbppl_fused_kernel<<<grid, block, 0, stream>>>(
        gt_padded, prop_boxes, pred_boxes, class_logits,
        gt_masks, gt_classes, out_cls, out_proj);
}

// Round 3
// 15.197 us; speedup vs baseline: 2.3876x; 1.0404x over previous
//
#include <hip/hip_runtime.h>

// Problem constants (from reference)
#define N_ 16
#define A_ 4096
#define G_ 256
#define C_ 80
#define ALPHA_ 0.25f
#define BIG_ 1e8f

// 8 lanes cooperate per anchor: sub = lane & 7.
//  - g-loop split stride-8 across subs (8 consecutive float4 LDS reads = 32
//    distinct banks, conflict-free, broadcast across anchors)
//  - class-loop split as interleaved float2 chunks (contiguous 64B per anchor)
//  - masked-out gt boxes are rewritten to (BIG,BIG,BIG,BIG) at staging:
//    their distance ~4e8 never wins the argmin; nonempty <=> mind < BIG;
//    when nonempty the winner is masked-in, so no mask gather needed.
// 32 anchors per 256-thread block -> 2048 blocks -> 8192 waves (100% occupancy)

__global__ __launch_bounds__(256) void cbppl_fused_kernel(
    const float* __restrict__ gt_padded,    // (N, G, 4)
    const float* __restrict__ prop_boxes,   // (N, A, 4)
    const float* __restrict__ pred_boxes,   // (N, A, 4)
    const float* __restrict__ class_logits, // (N, A, C)
    const int*   __restrict__ gt_masks,     // (N, G) bool->int32
    const int*   __restrict__ gt_classes,   // (N, G)
    float* __restrict__ out_cls,            // (N, A)
    float* __restrict__ out_proj)           // (N, A)
{
    __shared__ float4 s_gt[G_];
    __shared__ int    s_cls[G_];

    const int t   = threadIdx.x;
    const int n   = blockIdx.x >> 7;                     // 128 blocks per batch
    const int a   = ((blockIdx.x & 127) << 5) + (t >> 3); // 32 anchors per block
    const int sub = t & 7;

    // Stage gt data; fold mask into coordinates (G_ == blockDim.x == 256)
    {
        const int gi = n * G_ + t;
        float4 g4 = ((const float4*)gt_padded)[gi];
        if (!gt_masks[gi]) { g4.x = BIG_; g4.y = BIG_; g4.z = BIG_; g4.w = BIG_; }
        s_gt[t]  = g4;
        s_cls[t] = gt_classes[gi];
    }
    __syncthreads();

    // ---- Phase 1: argmin over prop distances (stride-8 split) ----
    const float4 pb = ((const float4*)prop_boxes)[n * A_ + a];

    float mind    = INFINITY;
    int   closest = 0;
    #pragma unroll 8
    for (int g = sub; g < G_; g += 8) {
        const float4 gb = s_gt[g];
        const float d = fabsf(pb.x - gb.x) + fabsf(pb.y - gb.y)
                      + fabsf(pb.z - gb.z) + fabsf(pb.w - gb.w);
        if (d < mind) { mind = d; closest = g; }  // increasing g -> first occurrence kept
    }
    // Cross-lane argmin over the 8 subs; tie -> smaller index (first occurrence)
    #pragma unroll
    for (int off = 1; off < 8; off <<= 1) {
        const float od = __shfl_xor(mind, off, 64);
        const int   oc = __shfl_xor(closest, off, 64);
        if (od < mind || (od == mind && oc < closest)) { mind = od; closest = oc; }
    }
    // masked-in d <= 4 << BIG; masked-out d ~ 4e8 > BIG
    const int nonempty = (mind < BIG_);

    // ---- Phase 2: projection loss at closest only ----
    const float4 qb = ((const float4*)pred_boxes)[n * A_ + a];
    const float4 cb = s_gt[closest];
    const float  pd = fabsf(qb.x - cb.x) + fabsf(qb.y - cb.y)
                    + fabsf(qb.z - cb.z) + fabsf(qb.w - cb.w);
    const float proj = nonempty ? pd : 0.0f;

    // ---- Phase 3: sigmoid focal loss, 10 classes per sub-lane ----
    const int target = nonempty ? s_cls[closest] : 0;

    const float2* lg2 = (const float2*)(class_logits + ((size_t)(n * A_ + a)) * C_);
    float acc = 0.0f;
    #pragma unroll
    for (int j = 0; j < 5; ++j) {
        const float2 x2 = lg2[sub + j * 8];
        const float xs[2] = {x2.x, x2.y};
        #pragma unroll
        for (int k = 0; k < 2; ++k) {
            const int   c  = (sub + j * 8) * 2 + k;
            const float x  = xs[k];
            const float oh = (c == target) ? 1.0f : 0.0f;
            const float ax = fabsf(x);
            const float e  = __expf(-ax);                       // exp(-|x|)
            const float ce = fmaxf(x, 0.0f) - x * oh + __logf(1.0f + e);
            const float r  = __builtin_amdgcn_rcpf(1.0f + e);
            const float p  = (x >= 0.0f) ? r : e * r;           // sigmoid(x)
            const float pt = oh ? p : (1.0f - p);
            const float om = 1.0f - pt;
            const float at = oh ? ALPHA_ : (1.0f - ALPHA_);
            acc += at * (ce * om * om);
        }
    }
    // Sum partial focal losses across the 8 subs
    acc += __shfl_xor(acc, 1, 64);
    acc += __shfl_xor(acc, 2, 64);
    acc += __shfl_xor(acc, 4, 64);

    if (sub == 0) {
        const int oidx = n * A_ + a;
        out_cls[oidx]  = nonempty ? acc * (1.0f / (float)C_) : 0.0f;
        out_proj[oidx] = proj;
    }
}

extern "C" void kernel_launch(void* const* d_in, const int* in_sizes, int n_in,
                              void* d_out, int out_size, void* d_ws, size_t ws_size,
                              hipStream_t stream) {
    const float* gt_padded    = (const float*)d_in[0];
    const float* prop_boxes   = (const float*)d_in[1];
    const float* pred_boxes   = (const float*)d_in[2];
    const float* class_logits = (const float*)d_in[3];
    const int*   gt_masks     = (const int*)d_in[4];
    const int*   gt_classes   = (const int*)d_in[5];

    float* out = (float*)d_out;
    float* out_cls  = out;             // classification_loss, (N, A)
    float* out_proj = out + N_ * A_;   // projection_loss,     (N, A)

    dim3 grid(N_ * A_ / 32);           // 2048 blocks, 32 anchors each
    dim3 block(256);
    cbppl_fused_kernel<<<grid, block, 0, stream>>>(
        gt_padded, prop_boxes, pred_boxes, class_logits,
        gt_masks, gt_classes, out_cls, out_proj);
}